// Round 19
// baseline (89.298 us; speedup 1.0000x reference)
//
#include <hip/hip_runtime.h>

// Problem constants (fixed by reference)
#define HW     4096
#define M_ROWS 32768        // N*H*W
#define OMD    112
#define OMP    128          // padded OM dim (stride, elements)

typedef __attribute__((ext_vector_type(8))) short short8;
typedef __attribute__((ext_vector_type(8), aligned(4))) short short8a;
typedef __attribute__((ext_vector_type(4))) float f32x4;

__device__ inline unsigned short f2bf(float f) {
  union { float f; unsigned int u; } v; v.f = f;
  unsigned int u = v.u;
  u += 0x7fffu + ((u >> 16) & 1u);      // RNE
  return (unsigned short)(u >> 16);
}
__device__ inline float bf2f(unsigned short h) {
  union { unsigned int u; float f; } v; v.u = ((unsigned int)h) << 16;
  return v.f;
}

// ---------------------------------------------------------------------------
// Fused prep (proven R5).
// ---------------------------------------------------------------------------
__global__ __launch_bounds__(256) void prep_fused(
    const float* __restrict__ x, const float* __restrict__ w_dw,
    const float* __restrict__ b_dw, const float* __restrict__ w_in,
    const float* __restrict__ w_out, const float* __restrict__ w_pw,
    const float* __restrict__ b_pw, unsigned short* __restrict__ xb,
    unsigned short* __restrict__ dwb, unsigned short* __restrict__ wi_b,
    unsigned short* __restrict__ wo_b, unsigned short* __restrict__ wp_b,
    float* __restrict__ bpw_pad) {
  int bid = blockIdx.x;
  int tid = threadIdx.x;
  if (bid < 8192) {
    int idx = bid * 256 + tid;                 // (pixel, c/4): 32768*64
    int c4 = (idx & 63) * 4;
    int pp = idx >> 6;
    int n = pp >> 12;
    int hw = pp & 4095;
    int h = hw >> 6, w = hw & 63;
    float4 bb = *(const float4*)&b_dw[c4];
    float a0 = bb.x, a1 = bb.y, a2 = bb.z, a3 = bb.w;
#pragma unroll
    for (int ky = 0; ky < 3; ++ky) {
      int iy = h + ky - 1;
      if (iy < 0 || iy > 63) continue;
#pragma unroll
      for (int kx = 0; kx < 3; ++kx) {
        int ix = w + kx - 1;
        if (ix < 0 || ix > 63) continue;
        float4 xv = *(const float4*)&x[((size_t)(n << 12) + iy * 64 + ix) * 256 + c4];
        float4 wv = *(const float4*)&w_dw[(ky * 3 + kx) * 256 + c4];
        a0 += xv.x * wv.x;
        a1 += xv.y * wv.y;
        a2 += xv.z * wv.z;
        a3 += xv.w * wv.w;
      }
    }
    ushort4 o;
    o.x = f2bf(a0); o.y = f2bf(a1); o.z = f2bf(a2); o.w = f2bf(a3);
    *(ushort4*)&dwb[(size_t)pp * 256 + c4] = o;
    float4 cv = *(const float4*)&x[(size_t)pp * 256 + c4];
    ushort4 oc;
    oc.x = f2bf(cv.x); oc.y = f2bf(cv.y); oc.z = f2bf(cv.z); oc.w = f2bf(cv.w);
    *(ushort4*)&xb[(size_t)pp * 256 + c4] = oc;
  } else {
    int idx = (bid - 8192) * 256 + tid;
    if (idx < 65536) {
      wi_b[idx] = f2bf(w_in[idx]);
    } else if (idx < 131072) {
      int i = idx - 65536;
      wo_b[i] = f2bf(w_out[i]);
    } else if (idx < 131072 + OMP * 256) {
      int i = idx - 131072;
      int o = i >> 8;
      wp_b[i] = (o < OMD) ? f2bf(w_pw[i]) : (unsigned short)0;
    } else if (idx < 131072 + OMP * 256 + OMP) {
      int i = idx - (131072 + OMP * 256);
      bpw_pad[i] = (i < OMD) ? b_pw[i] : 0.f;
    }
  }
}

// ---------------------------------------------------------------------------
// Merged mid GEMMs, v2: A via LDS (BK=64, T2 swizzle, R18) + B DIRECT FROM
// GLOBAL TO REGISTERS (weights are L2-resident and block-shared; plain
// global_load_dwordx4 gets fine-grained vmcnt scheduling instead of the
// all-or-nothing barrier drain). LDS halved to 16 KB (A only).
// Blocks [0,256):   om = dwb @ wp_b^T + bpw (remapped 32-short slots)
// Blocks [256,768): vproj = xb @ wi_b^T + b_in (linear)
// ---------------------------------------------------------------------------
__global__ __launch_bounds__(256) void gemm_mid(
    const unsigned short* __restrict__ dwb, const unsigned short* __restrict__ wp_b,
    const float* __restrict__ bpw, unsigned short* __restrict__ om,
    const unsigned short* __restrict__ xb, const unsigned short* __restrict__ wi_b,
    const float* __restrict__ b_in, unsigned short* __restrict__ vproj) {
  __shared__ __align__(16) unsigned short As[128 * 64];  // 16 KB (A only)
  int tid = threadIdx.x;
  int wave = tid >> 6, lane = tid & 63;
  int wr = wave >> 1, wc = wave & 1;

  const unsigned short *A, *W;
  const float* bias;
  unsigned short* Cout;
  int NN, colB;
  size_t rowB;
  int bid = blockIdx.x;
  bool is_om = (bid < 256);
  if (is_om) {
    int swz = (bid & 7) * 32 + (bid >> 3);     // 256 % 8 == 0, bijective
    A = dwb; W = wp_b; bias = bpw; Cout = om; NN = 128;
    rowB = (size_t)swz * 128; colB = 0;
  } else {
    int b = bid - 256;
    int swz = (b & 7) * 64 + (b >> 3);         // 512 % 8 == 0, bijective
    A = xb; W = wi_b; bias = b_in; Cout = vproj; NN = 256;
    rowB = (size_t)(swz >> 1) * 128; colB = (swz & 1) * 128;
  }

  f32x4 acc[4][4];
#pragma unroll
  for (int m = 0; m < 4; ++m)
#pragma unroll
    for (int n = 0; n < 4; ++n) acc[m][n] = (f32x4)(0.f);

  int srow = lane >> 3;                            // 0..7
  int scol_sw = (((lane & 7) ^ (lane >> 3)) * 8);  // swizzled src col-block
  int r7 = lane & 7;                               // == fragment row & 7

  // B fragment base: col = colB + wc*64 + n*16 + (lane&15); k-offset (lane>>4)*8
  const unsigned short* wbase =
      W + ((size_t)(colB + wc * 64 + (lane & 15))) * 256 + (lane >> 4) * 8;

  for (int k0 = 0; k0 < 256; k0 += 64) {
#pragma unroll
    for (int jj = 0; jj < 4; ++jj) {
      int j = wave * 4 + jj;                   // rows 8j..8j+7
      const unsigned short* ga =
          A + (rowB + 8 * j + srow) * 256 + k0 + scol_sw;
      __builtin_amdgcn_global_load_lds(
          (const __attribute__((address_space(1))) unsigned int*)ga,
          (__attribute__((address_space(3))) unsigned int*)(As + j * 512),
          16, 0, 0);
    }
    __syncthreads();

#pragma unroll
    for (int kk = 0; kk < 2; ++kk) {           // two 32-wide sub-slabs
      short8 aF[4], bF[4];
#pragma unroll
      for (int n = 0; n < 4; ++n)
        bF[n] = *(const short8*)(wbase + n * 4096 + k0 + kk * 32);
#pragma unroll
      for (int m = 0; m < 4; ++m)
        aF[m] = *(const short8*)&As[(wr * 64 + m * 16 + (lane & 15)) * 64 +
                                    (((kk * 4 + (lane >> 4)) ^ r7) * 8)];
#pragma unroll
      for (int m = 0; m < 4; ++m)
#pragma unroll
        for (int n = 0; n < 4; ++n)
          acc[m][n] = __builtin_amdgcn_mfma_f32_16x16x32_bf16(
              aF[m], bF[n], acc[m][n], 0, 0, 0);
    }
    __syncthreads();
  }

#pragma unroll
  for (int n = 0; n < 4; ++n) {
    int c = colB + wc * 64 + n * 16 + (lane & 15);
    float bv = bias[c];
    int nc = c;
    if (is_om) {   // remap into 32-short per-(px,g) slots (R10-validated)
      if (c < 72)       nc = (c / 18) * 32 + (c % 18);
      else if (c < 108) { int u = c - 72;  nc = (u / 9) * 32 + 18 + (u % 9); }
      else              { int u = c - 108; nc = (u / 5) * 32 + 27 + (u % 5); }
    }
#pragma unroll
    for (int m = 0; m < 4; ++m) {
#pragma unroll
      for (int j = 0; j < 4; ++j) {
        size_t row = rowB + wr * 64 + m * 16 + (lane >> 4) * 4 + j;
        Cout[row * NN + nc] = f2bf(acc[m][n][j] + bv);
      }
    }
  }
}

// ---------------------------------------------------------------------------
// Deformable sampling v7 (R11 champion, verbatim).
// ---------------------------------------------------------------------------
__global__ __launch_bounds__(256) void deform_sample_v7(
    const unsigned short* __restrict__ vproj, const unsigned short* __restrict__ om,
    unsigned short* __restrict__ samp) {
  __shared__ __align__(16) unsigned short s_v[144 * 64];   // 18432 B
  __shared__ __align__(16) float s_cw[64 * 28];            // 7168 B

  int bid = blockIdx.x;
  int swz = (bid & 7) * 256 + (bid >> 3);   // 2048 % 8 == 0 -> bijective
  int n = swz >> 8;                          // image 0..7
  int rem = swz & 255;
  int tile = rem >> 2;                       // 0..63
  int g = rem & 3;                           // group 0..3
  int ty0 = (tile >> 3) << 3, tx0 = (tile & 7) << 3;
  int wy0 = ty0 - 2, wx0 = tx0 - 2;          // window origin (may be <0)

  int tid = threadIdx.x;
  int wave = tid >> 6, lane = tid & 63;

  const unsigned short* vimg = vproj + ((size_t)n << 12) * 256;

#pragma unroll
  for (int i = 0; i < 5; ++i) {
    int seg = i * 4 + wave;
    if (seg < 18) {
      int f = seg * 1024 + lane * 16;        // flat byte offset in window
      int cell = f >> 7;                      // 128 B per cell
      int inner = (f >> 1) & 63;              // short offset within cell
      int r = cell / 12, c = cell - r * 12;
      int gy = min(max(wy0 + r, 0), 63);
      int gx = min(max(wx0 + c, 0), 63);
      const unsigned short* src =
          vimg + (size_t)(gy * 64 + gx) * 256 + g * 64 + inner;
      __builtin_amdgcn_global_load_lds(
          (const __attribute__((address_space(1))) unsigned int*)src,
          (__attribute__((address_space(3))) unsigned int*)(s_v + seg * 512),
          16, 0, 0);
    }
  }

  if (tid < 64) {
    int pl = tid;
    int hy = ty0 + (pl >> 3), wx = tx0 + (pl & 7);
    int p = (n << 12) + hy * 64 + wx;
    const unsigned short* o = om + (size_t)p * OMP + g * 32;  // 64B slot
    short8 xy0 = *(const short8*)(o);          // taps 0-3 (x,y interleaved)
    short8 xy1 = *(const short8*)(o + 8);      // taps 4-7
    unsigned int xy8 = *(const unsigned int*)(o + 16);  // tap 8
    short8a mk = *(const short8a*)(o + 18);    // masks 0-7
    unsigned short mk8 = o[26];

    float4 z4 = make_float4(0.f, 0.f, 0.f, 0.f);
#pragma unroll
    for (int q = 0; q < 7; ++q) *(float4*)&s_cw[pl * 28 + q * 4] = z4;

#pragma unroll
    for (int k = 0; k < 9; ++k) {
      float ox, oy, msk;
      if (k < 4) {
        ox = bf2f((unsigned short)xy0[2 * k]);
        oy = bf2f((unsigned short)xy0[2 * k + 1]);
        msk = bf2f((unsigned short)mk[k]);
      } else if (k < 8) {
        ox = bf2f((unsigned short)xy1[2 * (k - 4)]);
        oy = bf2f((unsigned short)xy1[2 * (k - 4) + 1]);
        msk = bf2f((unsigned short)mk[k]);
      } else {
        ox = bf2f((unsigned short)(xy8 & 0xffffu));
        oy = bf2f((unsigned short)(xy8 >> 16));
        msk = bf2f(mk8);
      }
      float px = (float)(wx + (k % 3) - 1) + ox;
      float py = (float)(hy + (k / 3) - 1) + oy;
      float x0f = floorf(px), y0f = floorf(py);
      int x0 = (int)x0f, y0 = (int)y0f;
      float fx = px - x0f, fy = py - y0f;
      bool vx0 = (unsigned)x0 < 64u, vx1 = (unsigned)(x0 + 1) < 64u;
      bool vy0 = (unsigned)y0 < 64u, vy1 = (unsigned)(y0 + 1) < 64u;
      float w00 = (vy0 && vx0) ? (1.f - fx) * (1.f - fy) * msk : 0.f;
      float w01 = (vy0 && vx1) ? fx * (1.f - fy) * msk : 0.f;
      float w10 = (vy1 && vx0) ? (1.f - fx) * fy * msk : 0.f;
      float w11 = (vy1 && vx1) ? fx * fy * msk : 0.f;
      int cx0 = min(max(min(max(x0, 0), 63) - wx + 2, 0), 4);
      int cx1 = min(max(min(max(x0 + 1, 0), 63) - wx + 2, 0), 4);
      int cy0 = min(max(min(max(y0, 0), 63) - hy + 2, 0), 4);
      int cy1 = min(max(min(max(y0 + 1, 0), 63) - hy + 2, 0), 4);
      s_cw[pl * 28 + cy0 * 5 + cx0] += w00;
      s_cw[pl * 28 + cy0 * 5 + cx1] += w01;
      s_cw[pl * 28 + cy1 * 5 + cx0] += w10;
      s_cw[pl * 28 + cy1 * 5 + cx1] += w11;
    }
  }
  __syncthreads();   // window (vmcnt drained) + cell weights visible

  int sub = lane & 7;
  int chb = sub * 16;                         // channel byte offset

#pragma unroll
  for (int iter = 0; iter < 2; ++iter) {
    int pl = iter * 32 + wave * 8 + (lane >> 3);   // tile-local pixel 0..63
    int ly = pl >> 3, lx = pl & 7;
    int hy = ty0 + ly, wx = tx0 + lx;
    int p = (n << 12) + hy * 64 + wx;
    const char* vb = (const char*)s_v + (ly * 12 + lx) * 128 + chb;

    float cwv[28];
#pragma unroll
    for (int q = 0; q < 7; ++q)
      *(float4*)&cwv[q * 4] = *(const float4*)&s_cw[pl * 28 + q * 4];

    float acc[8];
#pragma unroll
    for (int j = 0; j < 8; ++j) acc[j] = 0.f;

#pragma unroll
    for (int c = 0; c < 25; ++c) {
      const int off = ((c / 5) * 12 + (c % 5)) * 128;  // compile-time imm
      short8 v = *(const short8*)(vb + off);
      float w = cwv[c];
#pragma unroll
      for (int j = 0; j < 8; ++j)
        acc[j] += w * bf2f((unsigned short)v[j]);
    }

    union { unsigned short s[8]; short8 v8; } o8;
#pragma unroll
    for (int j = 0; j < 8; ++j) o8.s[j] = f2bf(acc[j]);
    *(short8*)&samp[(size_t)p * 256 + g * 64 + sub * 8] = o8.v8;
  }
}

// ---------------------------------------------------------------------------
// Final GEMM, v2: A via LDS (BK=64 + swizzle) + B direct-to-registers.
// ---------------------------------------------------------------------------
__global__ __launch_bounds__(256) void gemm_out(
    const unsigned short* __restrict__ A, const unsigned short* __restrict__ W,
    const float* __restrict__ bias, float* __restrict__ Cout) {
  __shared__ __align__(16) unsigned short As[128 * 64];  // 16 KB
  int tid = threadIdx.x;
  int wave = tid >> 6, lane = tid & 63;
  int wr = wave >> 1, wc = wave & 1;

  int bid = blockIdx.x;
  int swz = (bid & 7) * 64 + (bid >> 3);
  size_t rowB = (size_t)(swz >> 1) * 128;
  int colB = (swz & 1) * 128;

  f32x4 acc[4][4];
#pragma unroll
  for (int m = 0; m < 4; ++m)
#pragma unroll
    for (int n = 0; n < 4; ++n) acc[m][n] = (f32x4)(0.f);

  int srow = lane >> 3;
  int scol_sw = (((lane & 7) ^ (lane >> 3)) * 8);
  int r7 = lane & 7;

  const unsigned short* wbase =
      W + ((size_t)(colB + wc * 64 + (lane & 15))) * 256 + (lane >> 4) * 8;

  for (int k0 = 0; k0 < 256; k0 += 64) {
#pragma unroll
    for (int jj = 0; jj < 4; ++jj) {
      int j = wave * 4 + jj;
      const unsigned short* ga =
          A + (rowB + 8 * j + srow) * 256 + k0 + scol_sw;
      __builtin_amdgcn_global_load_lds(
          (const __attribute__((address_space(1))) unsigned int*)ga,
          (__attribute__((address_space(3))) unsigned int*)(As + j * 512),
          16, 0, 0);
    }
    __syncthreads();

#pragma unroll
    for (int kk = 0; kk < 2; ++kk) {
      short8 aF[4], bF[4];
#pragma unroll
      for (int n = 0; n < 4; ++n)
        bF[n] = *(const short8*)(wbase + n * 4096 + k0 + kk * 32);
#pragma unroll
      for (int m = 0; m < 4; ++m)
        aF[m] = *(const short8*)&As[(wr * 64 + m * 16 + (lane & 15)) * 64 +
                                    (((kk * 4 + (lane >> 4)) ^ r7) * 8)];
#pragma unroll
      for (int m = 0; m < 4; ++m)
#pragma unroll
        for (int n = 0; n < 4; ++n)
          acc[m][n] = __builtin_amdgcn_mfma_f32_16x16x32_bf16(
              aF[m], bF[n], acc[m][n], 0, 0, 0);
    }
    __syncthreads();
  }

#pragma unroll
  for (int n = 0; n < 4; ++n) {
    int col = colB + wc * 64 + n * 16 + (lane & 15);
    float bv = bias[col];
#pragma unroll
    for (int m = 0; m < 4; ++m) {
#pragma unroll
      for (int j = 0; j < 4; ++j) {
        size_t row = rowB + wr * 64 + m * 16 + (lane >> 4) * 4 + j;
        Cout[row * 256 + col] = acc[m][n][j] + bv;
      }
    }
  }
}

// ---------------------------------------------------------------------------
extern "C" void kernel_launch(void* const* d_in, const int* in_sizes, int n_in,
                              void* d_out, int out_size, void* d_ws,
                              size_t ws_size, hipStream_t stream) {
  const float* x     = (const float*)d_in[0];
  const float* w_in  = (const float*)d_in[3];
  const float* b_in  = (const float*)d_in[4];
  const float* w_out = (const float*)d_in[5];
  const float* b_out = (const float*)d_in[6];
  const float* w_dw  = (const float*)d_in[7];
  const float* b_dw  = (const float*)d_in[8];
  const float* w_pw  = (const float*)d_in[9];
  const float* b_pw  = (const float*)d_in[10];
  float* out = (float*)d_out;
  char* ws = (char*)d_ws;

  unsigned short* xb    = (unsigned short*)(ws);                  // 16 MB
  unsigned short* dwb   = (unsigned short*)(ws + (16u << 20));    // 16 MB (dw -> samp)
  unsigned short* vproj = (unsigned short*)(ws + (32u << 20));    // 16 MB
  unsigned short* om    = (unsigned short*)(ws + (48u << 20));    // 8 MB (bf16, remapped)
  unsigned short* wi_b  = (unsigned short*)(ws + (56u << 20));    // 128 KB
  unsigned short* wo_b  = (unsigned short*)(ws + (56u << 20) + (128u << 10));
  unsigned short* wp_b  = (unsigned short*)(ws + (56u << 20) + (256u << 10)); // 64 KB
  float*          bpw   = (float*)(ws + (56u << 20) + (320u << 10));          // 512 B

  prep_fused<<<8834, 256, 0, stream>>>(x, w_dw, b_dw, w_in, w_out, w_pw, b_pw,
                                       xb, dwb, wi_b, wo_b, wp_b, bpw);
  gemm_mid<<<768, 256, 0, stream>>>(dwb, wp_b, bpw, om, xb, wi_b, b_in, vproj);
  deform_sample_v7<<<2048, 256, 0, stream>>>(vproj, om, dwb /* samp */);
  gemm_out<<<512, 256, 0, stream>>>(dwb, wo_b, b_out, out);
}

// Round 20
// 74.345 us; speedup vs baseline: 1.2011x; 1.2011x over previous
//
#include <hip/hip_runtime.h>

// Problem constants (fixed by reference)
#define HW     4096
#define M_ROWS 32768        // N*H*W
#define OMD    112
#define OMP    128          // padded OM dim (stride, elements)

typedef __attribute__((ext_vector_type(8))) short short8;
typedef __attribute__((ext_vector_type(8), aligned(4))) short short8a;
typedef __attribute__((ext_vector_type(4))) float f32x4;

__device__ inline unsigned short f2bf(float f) {
  union { float f; unsigned int u; } v; v.f = f;
  unsigned int u = v.u;
  u += 0x7fffu + ((u >> 16) & 1u);      // RNE
  return (unsigned short)(u >> 16);
}
__device__ inline float bf2f(unsigned short h) {
  union { unsigned int u; float f; } v; v.u = ((unsigned int)h) << 16;
  return v.f;
}

// ---------------------------------------------------------------------------
// Fused prep (proven R5): depthwise 3x3 (fp32 x in, bf16 out) + xb=bf16(x)
// + weight/bias conversions. ~80 MB traffic at ~5.9 TB/s -> near HBM roofline.
// ---------------------------------------------------------------------------
__global__ __launch_bounds__(256) void prep_fused(
    const float* __restrict__ x, const float* __restrict__ w_dw,
    const float* __restrict__ b_dw, const float* __restrict__ w_in,
    const float* __restrict__ w_out, const float* __restrict__ w_pw,
    const float* __restrict__ b_pw, unsigned short* __restrict__ xb,
    unsigned short* __restrict__ dwb, unsigned short* __restrict__ wi_b,
    unsigned short* __restrict__ wo_b, unsigned short* __restrict__ wp_b,
    float* __restrict__ bpw_pad) {
  int bid = blockIdx.x;
  int tid = threadIdx.x;
  if (bid < 8192) {
    int idx = bid * 256 + tid;                 // (pixel, c/4): 32768*64
    int c4 = (idx & 63) * 4;
    int pp = idx >> 6;
    int n = pp >> 12;
    int hw = pp & 4095;
    int h = hw >> 6, w = hw & 63;
    float4 bb = *(const float4*)&b_dw[c4];
    float a0 = bb.x, a1 = bb.y, a2 = bb.z, a3 = bb.w;
#pragma unroll
    for (int ky = 0; ky < 3; ++ky) {
      int iy = h + ky - 1;
      if (iy < 0 || iy > 63) continue;
#pragma unroll
      for (int kx = 0; kx < 3; ++kx) {
        int ix = w + kx - 1;
        if (ix < 0 || ix > 63) continue;
        float4 xv = *(const float4*)&x[((size_t)(n << 12) + iy * 64 + ix) * 256 + c4];
        float4 wv = *(const float4*)&w_dw[(ky * 3 + kx) * 256 + c4];
        a0 += xv.x * wv.x;
        a1 += xv.y * wv.y;
        a2 += xv.z * wv.z;
        a3 += xv.w * wv.w;
      }
    }
    ushort4 o;
    o.x = f2bf(a0); o.y = f2bf(a1); o.z = f2bf(a2); o.w = f2bf(a3);
    *(ushort4*)&dwb[(size_t)pp * 256 + c4] = o;
    float4 cv = *(const float4*)&x[(size_t)pp * 256 + c4];
    ushort4 oc;
    oc.x = f2bf(cv.x); oc.y = f2bf(cv.y); oc.z = f2bf(cv.z); oc.w = f2bf(cv.w);
    *(ushort4*)&xb[(size_t)pp * 256 + c4] = oc;
  } else {
    int idx = (bid - 8192) * 256 + tid;
    if (idx < 65536) {
      wi_b[idx] = f2bf(w_in[idx]);
    } else if (idx < 131072) {
      int i = idx - 65536;
      wo_b[i] = f2bf(w_out[i]);
    } else if (idx < 131072 + OMP * 256) {
      int i = idx - 131072;
      int o = i >> 8;
      wp_b[i] = (o < OMD) ? f2bf(w_pw[i]) : (unsigned short)0;
    } else if (idx < 131072 + OMP * 256 + OMP) {
      int i = idx - (131072 + OMP * 256);
      bpw_pad[i] = (i < OMD) ? b_pw[i] : 0.f;
    }
  }
}

// ---------------------------------------------------------------------------
// Merged mid GEMMs, BK=64 + T2 XOR SWIZZLE (R17 diagnosis: 16-way conflict
// on fragment reads at 128B row stride; R18 fix).
// Layout: LDS slot (row, cb) holds global col-block cb ^ (row&7).
// Write: linear global_load_lds dest + pre-swizzled SOURCE col-block
//   (lane&7)^(lane>>3)  [staging rows 8-aligned -> row&7 == lane>>3].
// Read: As[row*64 + (((kk*4+(lane>>4)) ^ (lane&7))*8)] -> 2-way (free).
// Blocks [0,256):   om = dwb @ wp_b^T + bpw (remapped 32-short slots)
// Blocks [256,768): vproj = xb @ wi_b^T + b_in (linear)
// ---------------------------------------------------------------------------
__global__ __launch_bounds__(256) void gemm_mid(
    const unsigned short* __restrict__ dwb, const unsigned short* __restrict__ wp_b,
    const float* __restrict__ bpw, unsigned short* __restrict__ om,
    const unsigned short* __restrict__ xb, const unsigned short* __restrict__ wi_b,
    const float* __restrict__ b_in, unsigned short* __restrict__ vproj) {
  __shared__ __align__(16) unsigned short As[128 * 64];  // 16 KB
  __shared__ __align__(16) unsigned short Bs[128 * 64];  // 16 KB
  int tid = threadIdx.x;
  int wave = tid >> 6, lane = tid & 63;
  int wr = wave >> 1, wc = wave & 1;

  const unsigned short *A, *W;
  const float* bias;
  unsigned short* Cout;
  int NN, colB;
  size_t rowB;
  int bid = blockIdx.x;
  bool is_om = (bid < 256);
  if (is_om) {
    int swz = (bid & 7) * 32 + (bid >> 3);     // 256 % 8 == 0, bijective
    A = dwb; W = wp_b; bias = bpw; Cout = om; NN = 128;
    rowB = (size_t)swz * 128; colB = 0;
  } else {
    int b = bid - 256;
    int swz = (b & 7) * 64 + (b >> 3);         // 512 % 8 == 0, bijective
    A = xb; W = wi_b; bias = b_in; Cout = vproj; NN = 256;
    rowB = (size_t)(swz >> 1) * 128; colB = (swz & 1) * 128;
  }

  f32x4 acc[4][4];
#pragma unroll
  for (int m = 0; m < 4; ++m)
#pragma unroll
    for (int n = 0; n < 4; ++n) acc[m][n] = (f32x4)(0.f);

  int srow = lane >> 3;                            // 0..7
  int scol_sw = (((lane & 7) ^ (lane >> 3)) * 8);  // swizzled src col-block
  int r7 = lane & 7;                               // == fragment row & 7

  for (int k0 = 0; k0 < 256; k0 += 64) {
#pragma unroll
    for (int jj = 0; jj < 4; ++jj) {
      int j = wave * 4 + jj;                   // rows 8j..8j+7
      const unsigned short* ga =
          A + (rowB + 8 * j + srow) * 256 + k0 + scol_sw;
      __builtin_amdgcn_global_load_lds(
          (const __attribute__((address_space(1))) unsigned int*)ga,
          (__attribute__((address_space(3))) unsigned int*)(As + j * 512),
          16, 0, 0);
      const unsigned short* gb =
          W + ((size_t)(colB + 8 * j + srow)) * 256 + k0 + scol_sw;
      __builtin_amdgcn_global_load_lds(
          (const __attribute__((address_space(1))) unsigned int*)gb,
          (__attribute__((address_space(3))) unsigned int*)(Bs + j * 512),
          16, 0, 0);
    }
    __syncthreads();

#pragma unroll
    for (int kk = 0; kk < 2; ++kk) {           // two 32-wide sub-slabs
      short8 aF[4], bF[4];
#pragma unroll
      for (int m = 0; m < 4; ++m)
        aF[m] = *(const short8*)&As[(wr * 64 + m * 16 + (lane & 15)) * 64 +
                                    (((kk * 4 + (lane >> 4)) ^ r7) * 8)];
#pragma unroll
      for (int n = 0; n < 4; ++n)
        bF[n] = *(const short8*)&Bs[(wc * 64 + n * 16 + (lane & 15)) * 64 +
                                    (((kk * 4 + (lane >> 4)) ^ r7) * 8)];
#pragma unroll
      for (int m = 0; m < 4; ++m)
#pragma unroll
        for (int n = 0; n < 4; ++n)
          acc[m][n] = __builtin_amdgcn_mfma_f32_16x16x32_bf16(
              aF[m], bF[n], acc[m][n], 0, 0, 0);
    }
    __syncthreads();
  }

#pragma unroll
  for (int n = 0; n < 4; ++n) {
    int c = colB + wc * 64 + n * 16 + (lane & 15);
    float bv = bias[c];
    int nc = c;
    if (is_om) {   // remap into 32-short per-(px,g) slots (R10-validated)
      if (c < 72)       nc = (c / 18) * 32 + (c % 18);
      else if (c < 108) { int u = c - 72;  nc = (u / 9) * 32 + 18 + (u % 9); }
      else              { int u = c - 108; nc = (u / 5) * 32 + 27 + (u % 5); }
    }
#pragma unroll
    for (int m = 0; m < 4; ++m) {
#pragma unroll
      for (int j = 0; j < 4; ++j) {
        size_t row = rowB + wr * 64 + m * 16 + (lane >> 4) * 4 + j;
        Cout[row * NN + nc] = f2bf(acc[m][n][j] + bv);
      }
    }
  }
}

// ---------------------------------------------------------------------------
// Deformable sampling v7 (R11 champion): 5x5 cell-weight pre-accumulation
// (exact reassociation of 36 tap-corner weights into 25 per-cell weights);
// LDS-staged 12x12x64ch window; inner loop = 25 ds_read_b128 with
// compile-time immediate offsets. 2048 blocks x 4 waves;
// block = (image, 8x8 tile, group); XCD-chunked swizzle.
// ---------------------------------------------------------------------------
__global__ __launch_bounds__(256) void deform_sample_v7(
    const unsigned short* __restrict__ vproj, const unsigned short* __restrict__ om,
    unsigned short* __restrict__ samp) {
  __shared__ __align__(16) unsigned short s_v[144 * 64];   // 18432 B
  __shared__ __align__(16) float s_cw[64 * 28];            // 7168 B

  int bid = blockIdx.x;
  int swz = (bid & 7) * 256 + (bid >> 3);   // 2048 % 8 == 0 -> bijective
  int n = swz >> 8;                          // image 0..7
  int rem = swz & 255;
  int tile = rem >> 2;                       // 0..63
  int g = rem & 3;                           // group 0..3
  int ty0 = (tile >> 3) << 3, tx0 = (tile & 7) << 3;
  int wy0 = ty0 - 2, wx0 = tx0 - 2;          // window origin (may be <0)

  int tid = threadIdx.x;
  int wave = tid >> 6, lane = tid & 63;

  const unsigned short* vimg = vproj + ((size_t)n << 12) * 256;

#pragma unroll
  for (int i = 0; i < 5; ++i) {
    int seg = i * 4 + wave;
    if (seg < 18) {
      int f = seg * 1024 + lane * 16;        // flat byte offset in window
      int cell = f >> 7;                      // 128 B per cell
      int inner = (f >> 1) & 63;              // short offset within cell
      int r = cell / 12, c = cell - r * 12;
      int gy = min(max(wy0 + r, 0), 63);
      int gx = min(max(wx0 + c, 0), 63);
      const unsigned short* src =
          vimg + (size_t)(gy * 64 + gx) * 256 + g * 64 + inner;
      __builtin_amdgcn_global_load_lds(
          (const __attribute__((address_space(1))) unsigned int*)src,
          (__attribute__((address_space(3))) unsigned int*)(s_v + seg * 512),
          16, 0, 0);
    }
  }

  if (tid < 64) {
    int pl = tid;
    int hy = ty0 + (pl >> 3), wx = tx0 + (pl & 7);
    int p = (n << 12) + hy * 64 + wx;
    const unsigned short* o = om + (size_t)p * OMP + g * 32;  // 64B slot
    short8 xy0 = *(const short8*)(o);          // taps 0-3 (x,y interleaved)
    short8 xy1 = *(const short8*)(o + 8);      // taps 4-7
    unsigned int xy8 = *(const unsigned int*)(o + 16);  // tap 8
    short8a mk = *(const short8a*)(o + 18);    // masks 0-7
    unsigned short mk8 = o[26];

    float4 z4 = make_float4(0.f, 0.f, 0.f, 0.f);
#pragma unroll
    for (int q = 0; q < 7; ++q) *(float4*)&s_cw[pl * 28 + q * 4] = z4;

#pragma unroll
    for (int k = 0; k < 9; ++k) {
      float ox, oy, msk;
      if (k < 4) {
        ox = bf2f((unsigned short)xy0[2 * k]);
        oy = bf2f((unsigned short)xy0[2 * k + 1]);
        msk = bf2f((unsigned short)mk[k]);
      } else if (k < 8) {
        ox = bf2f((unsigned short)xy1[2 * (k - 4)]);
        oy = bf2f((unsigned short)xy1[2 * (k - 4) + 1]);
        msk = bf2f((unsigned short)mk[k]);
      } else {
        ox = bf2f((unsigned short)(xy8 & 0xffffu));
        oy = bf2f((unsigned short)(xy8 >> 16));
        msk = bf2f(mk8);
      }
      float px = (float)(wx + (k % 3) - 1) + ox;
      float py = (float)(hy + (k / 3) - 1) + oy;
      float x0f = floorf(px), y0f = floorf(py);
      int x0 = (int)x0f, y0 = (int)y0f;
      float fx = px - x0f, fy = py - y0f;
      bool vx0 = (unsigned)x0 < 64u, vx1 = (unsigned)(x0 + 1) < 64u;
      bool vy0 = (unsigned)y0 < 64u, vy1 = (unsigned)(y0 + 1) < 64u;
      float w00 = (vy0 && vx0) ? (1.f - fx) * (1.f - fy) * msk : 0.f;
      float w01 = (vy0 && vx1) ? fx * (1.f - fy) * msk : 0.f;
      float w10 = (vy1 && vx0) ? (1.f - fx) * fy * msk : 0.f;
      float w11 = (vy1 && vx1) ? fx * fy * msk : 0.f;
      int cx0 = min(max(min(max(x0, 0), 63) - wx + 2, 0), 4);
      int cx1 = min(max(min(max(x0 + 1, 0), 63) - wx + 2, 0), 4);
      int cy0 = min(max(min(max(y0, 0), 63) - hy + 2, 0), 4);
      int cy1 = min(max(min(max(y0 + 1, 0), 63) - hy + 2, 0), 4);
      s_cw[pl * 28 + cy0 * 5 + cx0] += w00;
      s_cw[pl * 28 + cy0 * 5 + cx1] += w01;
      s_cw[pl * 28 + cy1 * 5 + cx0] += w10;
      s_cw[pl * 28 + cy1 * 5 + cx1] += w11;
    }
  }
  __syncthreads();   // window (vmcnt drained) + cell weights visible

  int sub = lane & 7;
  int chb = sub * 16;                         // channel byte offset

#pragma unroll
  for (int iter = 0; iter < 2; ++iter) {
    int pl = iter * 32 + wave * 8 + (lane >> 3);   // tile-local pixel 0..63
    int ly = pl >> 3, lx = pl & 7;
    int hy = ty0 + ly, wx = tx0 + lx;
    int p = (n << 12) + hy * 64 + wx;
    const char* vb = (const char*)s_v + (ly * 12 + lx) * 128 + chb;

    float cwv[28];
#pragma unroll
    for (int q = 0; q < 7; ++q)
      *(float4*)&cwv[q * 4] = *(const float4*)&s_cw[pl * 28 + q * 4];

    float acc[8];
#pragma unroll
    for (int j = 0; j < 8; ++j) acc[j] = 0.f;

#pragma unroll
    for (int c = 0; c < 25; ++c) {
      const int off = ((c / 5) * 12 + (c % 5)) * 128;  // compile-time imm
      short8 v = *(const short8*)(vb + off);
      float w = cwv[c];
#pragma unroll
      for (int j = 0; j < 8; ++j)
        acc[j] += w * bf2f((unsigned short)v[j]);
    }

    union { unsigned short s[8]; short8 v8; } o8;
#pragma unroll
    for (int j = 0; j < 8; ++j) o8.s[j] = f2bf(acc[j]);
    *(short8*)&samp[(size_t)p * 256 + g * 64 + sub * 8] = o8.v8;
  }
}

// ---------------------------------------------------------------------------
// Final GEMM, BK=64 + T2 XOR swizzle (same structure as gemm_mid).
// out[32768,256](fp32) = samp @ wo_b^T + b_out.
// ---------------------------------------------------------------------------
__global__ __launch_bounds__(256) void gemm_out(
    const unsigned short* __restrict__ A, const unsigned short* __restrict__ W,
    const float* __restrict__ bias, float* __restrict__ Cout) {
  __shared__ __align__(16) unsigned short As[128 * 64];
  __shared__ __align__(16) unsigned short Bs[128 * 64];
  int tid = threadIdx.x;
  int wave = tid >> 6, lane = tid & 63;
  int wr = wave >> 1, wc = wave & 1;

  int bid = blockIdx.x;
  int swz = (bid & 7) * 64 + (bid >> 3);
  size_t rowB = (size_t)(swz >> 1) * 128;
  int colB = (swz & 1) * 128;

  f32x4 acc[4][4];
#pragma unroll
  for (int m = 0; m < 4; ++m)
#pragma unroll
    for (int n = 0; n < 4; ++n) acc[m][n] = (f32x4)(0.f);

  int srow = lane >> 3;
  int scol_sw = (((lane & 7) ^ (lane >> 3)) * 8);
  int r7 = lane & 7;

  for (int k0 = 0; k0 < 256; k0 += 64) {
#pragma unroll
    for (int jj = 0; jj < 4; ++jj) {
      int j = wave * 4 + jj;
      const unsigned short* ga =
          A + (rowB + 8 * j + srow) * 256 + k0 + scol_sw;
      __builtin_amdgcn_global_load_lds(
          (const __attribute__((address_space(1))) unsigned int*)ga,
          (__attribute__((address_space(3))) unsigned int*)(As + j * 512),
          16, 0, 0);
      const unsigned short* gb =
          W + ((size_t)(colB + 8 * j + srow)) * 256 + k0 + scol_sw;
      __builtin_amdgcn_global_load_lds(
          (const __attribute__((address_space(1))) unsigned int*)gb,
          (__attribute__((address_space(3))) unsigned int*)(Bs + j * 512),
          16, 0, 0);
    }
    __syncthreads();

#pragma unroll
    for (int kk = 0; kk < 2; ++kk) {
      short8 aF[4], bF[4];
#pragma unroll
      for (int m = 0; m < 4; ++m)
        aF[m] = *(const short8*)&As[(wr * 64 + m * 16 + (lane & 15)) * 64 +
                                    (((kk * 4 + (lane >> 4)) ^ r7) * 8)];
#pragma unroll
      for (int n = 0; n < 4; ++n)
        bF[n] = *(const short8*)&Bs[(wc * 64 + n * 16 + (lane & 15)) * 64 +
                                    (((kk * 4 + (lane >> 4)) ^ r7) * 8)];
#pragma unroll
      for (int m = 0; m < 4; ++m)
#pragma unroll
        for (int n = 0; n < 4; ++n)
          acc[m][n] = __builtin_amdgcn_mfma_f32_16x16x32_bf16(
              aF[m], bF[n], acc[m][n], 0, 0, 0);
    }
    __syncthreads();
  }

#pragma unroll
  for (int n = 0; n < 4; ++n) {
    int col = colB + wc * 64 + n * 16 + (lane & 15);
    float bv = bias[col];
#pragma unroll
    for (int m = 0; m < 4; ++m) {
#pragma unroll
      for (int j = 0; j < 4; ++j) {
        size_t row = rowB + wr * 64 + m * 16 + (lane >> 4) * 4 + j;
        Cout[row * 256 + col] = acc[m][n][j] + bv;
      }
    }
  }
}

// ---------------------------------------------------------------------------
extern "C" void kernel_launch(void* const* d_in, const int* in_sizes, int n_in,
                              void* d_out, int out_size, void* d_ws,
                              size_t ws_size, hipStream_t stream) {
  const float* x     = (const float*)d_in[0];
  const float* w_in  = (const float*)d_in[3];
  const float* b_in  = (const float*)d_in[4];
  const float* w_out = (const float*)d_in[5];
  const float* b_out = (const float*)d_in[6];
  const float* w_dw  = (const float*)d_in[7];
  const float* b_dw  = (const float*)d_in[8];
  const float* w_pw  = (const float*)d_in[9];
  const float* b_pw  = (const float*)d_in[10];
  float* out = (float*)d_out;
  char* ws = (char*)d_ws;

  unsigned short* xb    = (unsigned short*)(ws);                  // 16 MB
  unsigned short* dwb   = (unsigned short*)(ws + (16u << 20));    // 16 MB (dw -> samp)
  unsigned short* vproj = (unsigned short*)(ws + (32u << 20));    // 16 MB
  unsigned short* om    = (unsigned short*)(ws + (48u << 20));    // 8 MB (bf16, remapped)
  unsigned short* wi_b  = (unsigned short*)(ws + (56u << 20));    // 128 KB
  unsigned short* wo_b  = (unsigned short*)(ws + (56u << 20) + (128u << 10));
  unsigned short* wp_b  = (unsigned short*)(ws + (56u << 20) + (256u << 10)); // 64 KB
  float*          bpw   = (float*)(ws + (56u << 20) + (320u << 10));          // 512 B

  prep_fused<<<8834, 256, 0, stream>>>(x, w_dw, b_dw, w_in, w_out, w_pw, b_pw,
                                       xb, dwb, wi_b, wo_b, wp_b, bpw);
  gemm_mid<<<768, 256, 0, stream>>>(dwb, wp_b, bpw, om, xb, wi_b, b_in, vproj);
  deform_sample_v7<<<2048, 256, 0, stream>>>(vproj, om, dwb /* samp */);
  gemm_out<<<512, 256, 0, stream>>>(dwb, wo_b, b_out, out);
}